// Round 5
// baseline (1016.470 us; speedup 1.0000x reference)
//
#include <hip/hip_runtime.h>
#include <math.h>

#define B_      16
#define C_      512
#define HW_     4096
#define P_      1024
#define EPSN    1e-4f
#define TEMP_   20.0f
#define THRESH_ 0.95f
#define NEGINF_ -1e9f
#define TIE_THR 1e-3f

#define PRED_OFF   0
#define ASSIGN_OFF 65536
#define GRID_OFF   131072

typedef short short8 __attribute__((ext_vector_type(8)));
typedef float f32x16 __attribute__((ext_vector_type(16)));

__device__ inline unsigned short f2bf(float f) {
    unsigned u = __float_as_uint(f);
    unsigned r = u + 0x7fffu + ((u >> 16) & 1u);
    return (unsigned short)(r >> 16);
}
__device__ inline float bf2f(unsigned short h) {
    return __uint_as_float((unsigned)h << 16);
}

// ---------------- pool sup_y -> proto_grid + valid ----------------
__global__ void pool_y_kernel(const float* __restrict__ sup_y,
                              float* __restrict__ out_grid,
                              float* __restrict__ validf) {
    int p = blockIdx.x * blockDim.x + threadIdx.x;
    if (p >= P_) return;
    int b = p >> 6, cell = p & 63, gy = cell >> 3, gx = cell & 7;
    const float* base = sup_y + b * HW_ + gy * 8 * 64 + gx * 8;
    float s = 0.f;
    #pragma unroll
    for (int r = 0; r < 8; ++r)
        #pragma unroll
        for (int c = 0; c < 8; ++c) s += base[r * 64 + c];
    float avg = s * (1.0f / 64.0f);
    out_grid[p] = (avg < THRESH_) ? 0.0f : avg;
    validf[p]   = (avg > THRESH_) ? 1.0f : 0.0f;
}

// ---------------- pool sup_x -> pooledT[c][p], float4 loads ----------------
__global__ __launch_bounds__(256) void pool_x_kernel(const float* __restrict__ sup_x,
                                                     float* __restrict__ pooledT) {
    int blk = blockIdx.x * 4 + (threadIdx.x >> 6);   // b*C_ + c
    int b = blk >> 9, c = blk & 511;
    int lane = threadIdx.x & 63;
    int cq = lane & 15, rq = lane >> 4;
    const float* base = sup_x + (size_t)(b * C_ + c) * HW_;
    float acc[8];
    #pragma unroll
    for (int g = 0; g < 8; ++g) acc[g] = 0.f;
    #pragma unroll
    for (int i = 0; i < 16; ++i) {
        int row = 4 * i + rq;
        float4 v = *(const float4*)(base + row * 64 + cq * 4);
        acc[i >> 1] += (v.x + v.y) + (v.z + v.w);
    }
    #pragma unroll
    for (int g = 0; g < 8; ++g) {
        acc[g] += __shfl_xor(acc[g], 1);    // cq pair within gx
        acc[g] += __shfl_xor(acc[g], 16);   // rq
        acc[g] += __shfl_xor(acc[g], 32);   // rq
    }
    if (rq == 0 && (cq & 1) == 0) {
        int gx = cq >> 1;
        #pragma unroll
        for (int gy = 0; gy < 8; ++gy)
            pooledT[c * P_ + b * 64 + gy * 8 + gx] = acc[gy] * (1.0f / 64.0f);
    }
}

// ---------------- merged: pack protos to MFMA B order + per-proto 1/norm ----
__global__ __launch_bounds__(512) void pack_b_kernel(const float* __restrict__ pooledT,
                                                     const float* __restrict__ validf,
                                                     short* __restrict__ Bph,
                                                     short* __restrict__ Bpl,
                                                     float* __restrict__ rnv) {
    __shared__ double ssred[8][64];
    int nl = threadIdx.x & 63;
    int w  = threadIdx.x >> 6;            // 0..7 -> channel chunk
    int n  = blockIdx.x * 64 + nl;
    double ss = 0.0;
    for (int c8i = 0; c8i < 8; ++c8i) {
        int c8 = w * 8 + c8i;
        unsigned short vh[8], vl[8];
        #pragma unroll
        for (int j = 0; j < 8; ++j) {
            float p = pooledT[(c8 * 8 + j) * P_ + n];
            ss += (double)p * (double)p;
            unsigned short h = f2bf(p);
            vh[j] = h;
            vl[j] = f2bf(p - bf2f(h));
        }
        uint4 uh, ul;
        uh.x = (unsigned)vh[0] | ((unsigned)vh[1] << 16);
        uh.y = (unsigned)vh[2] | ((unsigned)vh[3] << 16);
        uh.z = (unsigned)vh[4] | ((unsigned)vh[5] << 16);
        uh.w = (unsigned)vh[6] | ((unsigned)vh[7] << 16);
        ul.x = (unsigned)vl[0] | ((unsigned)vl[1] << 16);
        ul.y = (unsigned)vl[2] | ((unsigned)vl[3] << 16);
        ul.z = (unsigned)vl[4] | ((unsigned)vl[5] << 16);
        ul.w = (unsigned)vl[6] | ((unsigned)vl[7] << 16);
        int sk = c8 >> 1, kh = c8 & 1;
        *(uint4*)&Bph[sk * 16384 + n * 16 + kh * 8] = uh;
        *(uint4*)&Bpl[sk * 16384 + n * 16 + kh * 8] = ul;
    }
    ssred[w][nl] = ss;
    __syncthreads();
    if (threadIdx.x < 64) {
        double s = 0.0;
        #pragma unroll
        for (int q = 0; q < 8; ++q) s += ssred[q][threadIdx.x];
        int nn = blockIdx.x * 64 + threadIdx.x;
        float rn = 1.0f / fmaxf((float)sqrt(s), EPSN);
        rnv[nn] = (validf[nn] > 0.5f) ? rn : 0.0f;
    }
}

// ---------------- fused MFMA GEMM + softmax + argmax ----------------
// grid 1024 blocks (64 pixels each), 512 threads (8 waves).
// K-TILED A panel: 4 tiles x 128 channels; Ah+Al = 32 KB LDS (fragment order,
// conflict-free ds_read_b128). 2 barriers per tile. Occupancy: ~33 KB LDS ->
// 3-4 blocks/CU (6-8 waves/SIMD) vs round-2's 1 block/CU — the latency cover
// the 128 KB version lacked. Same staging math / MFMA order as round 2/3 ->
// bit-identical outputs. B register ping-prefetch from L2 across tiles.
// 3-pass split: dist = ah*bh + al*bh + ah*bl.
__global__ __launch_bounds__(512, 2) void gemm_fused_kernel(
        const float* __restrict__ qry,
        const short* __restrict__ Bph,
        const short* __restrict__ Bpl,
        const float* __restrict__ pooledT,
        const float* __restrict__ rnv,
        float* __restrict__ out) {
    __shared__ short A_lds[16 * 64 * 8 * 2];   // 32 KB: Ah @0, Al @8192 (shorts)
    __shared__ float rqs_lds[64];
    __shared__ int rowinfo[64];
    // post-K-loop aliases into the (dead) A_lds region:
    float* ss_part = (float*)A_lds;            // [512*4]  bytes 0..8191
    float* stbuf   = (float*)A_lds + 2048;     // [64*8*6] bytes 8192..20479

    int m0 = blockIdx.x * 64;
    int b = m0 >> 12;
    int hw0 = m0 & 4095;
    int tid = threadIdx.x;
    int w = tid >> 6;
    int lane = tid & 63;
    int hl = lane & 31, half = lane >> 5;
    int nb = w * 128;

    const float* qb = qry + (size_t)b * (C_ * HW_) + hw0;
    const short* bh_base = Bph + ((nb + hl) * 16 + half * 8);
    const short* bl_base = Bpl + ((nb + hl) * 16 + half * 8);

    f32x16 zero16 = {0.f,0.f,0.f,0.f,0.f,0.f,0.f,0.f,0.f,0.f,0.f,0.f,0.f,0.f,0.f,0.f};
    f32x16 acc[2][4];
    #pragma unroll
    for (int mt = 0; mt < 2; ++mt)
        #pragma unroll
        for (int nt = 0; nt < 4; ++nt) acc[mt][nt] = zero16;

    // ---- B prologue prefetch (sk = 0), independent of LDS ----
    short8 bhc[4], blc[4];
    #pragma unroll
    for (int nt = 0; nt < 4; ++nt) {
        bhc[nt] = *(const short8*)(bh_base + nt * 512);
        blc[nt] = *(const short8*)(bl_base + nt * 512);
    }

    int pg = tid & 15;          // pixel quad
    int u  = tid >> 4;          // 0..31 -> channel-octet id (c8 = u or u+32)
    float ss4[4] = {0.f, 0.f, 0.f, 0.f};
    short8 ahc[2], alc[2];

    for (int T = 0; T < 4; ++T) {
        if (T) __syncthreads();              // everyone done reading tile T-1
        // ---- stage tile T: channels c8 in [16T, 16T+16), by half the block ----
        if ((u >> 4) == (T & 1)) {
            int c8 = u + (T >> 1) * 32;      // T0:u<16 un=0; T1:u>=16 un=0; T2:u<16 un=1; T3:u>=16 un=1
            int c8l = c8 & 15;
            const float* src = qb + (size_t)(c8 * 8) * HW_ + pg * 4;
            float4 q[8];
            #pragma unroll
            for (int j = 0; j < 8; ++j)
                q[j] = *(const float4*)(src + (size_t)j * HW_);
            #pragma unroll
            for (int pp = 0; pp < 4; ++pp) {
                unsigned uh[4], ul[4];
                #pragma unroll
                for (int jj = 0; jj < 4; ++jj) {
                    float a0 = ((const float*)&q[2 * jj])[pp];
                    float a1 = ((const float*)&q[2 * jj + 1])[pp];
                    unsigned short h0 = f2bf(a0), h1 = f2bf(a1);
                    float r0 = a0 - bf2f(h0), r1 = a1 - bf2f(h1);
                    unsigned short l0 = f2bf(r0), l1 = f2bf(r1);
                    uh[jj] = (unsigned)h0 | ((unsigned)h1 << 16);
                    ul[jj] = (unsigned)l0 | ((unsigned)l1 << 16);
                    ss4[pp] += a0 * a0 + a1 * a1;
                }
                uint4 UH, UL;
                UH.x = uh[0]; UH.y = uh[1]; UH.z = uh[2]; UH.w = uh[3];
                UL.x = ul[0]; UL.y = ul[1]; UL.z = ul[2]; UL.w = ul[3];
                int off = (c8l * 64 + pg * 4 + pp) * 8;   // shorts, 16B aligned
                *(uint4*)&A_lds[off] = UH;
                *(uint4*)&A_lds[8192 + off] = UL;
            }
        }
        __syncthreads();

        // ---- A prologue read for this tile (s = 0 -> c8l = half) ----
        int ab0 = (half * 64 + hl) * 8;
        #pragma unroll
        for (int mt = 0; mt < 2; ++mt) {
            ahc[mt] = *(const short8*)&A_lds[ab0 + mt * 256];
            alc[mt] = *(const short8*)&A_lds[8192 + ab0 + mt * 256];
        }

        // ---- 8 K-steps on this tile, 1-deep A (LDS) + B (L2) prefetch ----
        for (int s = 0; s < 8; ++s) {
            int sk = T * 8 + s;
            int nsk = sk + 1;
            short8 bhn[4], bln[4], ahn[2], aln[2];
            if (nsk < 32) {
                const short* bh_p = bh_base + nsk * 16384;
                const short* bl_p = bl_base + nsk * 16384;
                #pragma unroll
                for (int nt = 0; nt < 4; ++nt) {
                    bhn[nt] = *(const short8*)(bh_p + nt * 512);
                    bln[nt] = *(const short8*)(bl_p + nt * 512);
                }
            }
            if (s < 7) {
                int abn = (((s + 1) * 2 + half) * 64 + hl) * 8;
                #pragma unroll
                for (int mt = 0; mt < 2; ++mt) {
                    ahn[mt] = *(const short8*)&A_lds[abn + mt * 256];
                    aln[mt] = *(const short8*)&A_lds[8192 + abn + mt * 256];
                }
            }
            #pragma unroll
            for (int nt = 0; nt < 4; ++nt) {
                #pragma unroll
                for (int mt = 0; mt < 2; ++mt) {
                    acc[mt][nt] = __builtin_amdgcn_mfma_f32_32x32x16_bf16(ahc[mt], bhc[nt], acc[mt][nt], 0, 0, 0);
                    acc[mt][nt] = __builtin_amdgcn_mfma_f32_32x32x16_bf16(alc[mt], bhc[nt], acc[mt][nt], 0, 0, 0);
                    acc[mt][nt] = __builtin_amdgcn_mfma_f32_32x32x16_bf16(ahc[mt], blc[nt], acc[mt][nt], 0, 0, 0);
                }
            }
            if (nsk < 32) {
                #pragma unroll
                for (int nt = 0; nt < 4; ++nt) { bhc[nt] = bhn[nt]; blc[nt] = bln[nt]; }
            }
            if (s < 7) {
                #pragma unroll
                for (int mt = 0; mt < 2; ++mt) { ahc[mt] = ahn[mt]; alc[mt] = aln[mt]; }
            }
        }
    }
    __syncthreads();   // A_lds dead; aliased scratch phase begins

    // ---- per-pixel 1/||q||: same partials + reduce order as rounds 2/3 ----
    *(float4*)&ss_part[tid * 4] = *(const float4*)ss4;
    __syncthreads();
    if (tid < 64) {
        int pg2 = tid >> 2, pp = tid & 3;
        float s = 0.f;
        #pragma unroll
        for (int k = 0; k < 32; ++k) s += ss_part[(pg2 + 16 * k) * 4 + pp];
        rqs_lds[tid] = 1.0f / fmaxf(sqrtf(s), EPSN);
    }
    __syncthreads();

    // ---- per-wave epilogue: scale, top2, softmax sums over this wave's 128 n ----
    float rn4[4];
    #pragma unroll
    for (int nt = 0; nt < 4; ++nt) rn4[nt] = rnv[nb + nt * 32 + hl];

    #pragma unroll
    for (int mt = 0; mt < 2; ++mt) {
        #pragma unroll
        for (int r = 0; r < 16; ++r) {
            int mrow = mt * 32 + (r & 3) + 8 * (r >> 2) + 4 * half;
            float scale = rqs_lds[mrow] * TEMP_;
            float d4[4], lg4[4];
            float v1 = -3e38f, v2 = -3e38f;
            int n1 = P_, n2 = P_;
            #pragma unroll
            for (int nt = 0; nt < 4; ++nt) {
                float dd = acc[mt][nt][r] * rn4[nt] * scale;
                float lg = (rn4[nt] > 0.f) ? dd : NEGINF_;
                d4[nt] = dd; lg4[nt] = lg;
                int n = nb + nt * 32 + hl;
                if (lg > v1 || (lg == v1 && n < n1)) {
                    v2 = v1; n2 = n1; v1 = lg; n1 = n;
                } else if (lg > v2 || (lg == v2 && n < n2)) {
                    v2 = lg; n2 = n;
                }
            }
            #pragma unroll
            for (int off = 1; off < 32; off <<= 1) {
                float ov1 = __shfl_xor(v1, off), ov2 = __shfl_xor(v2, off);
                int   on1 = __shfl_xor(n1, off), on2 = __shfl_xor(n2, off);
                if (ov1 > v1 || (ov1 == v1 && on1 < n1)) {
                    if (v1 > ov2 || (v1 == ov2 && n1 < on2)) { v2 = v1; n2 = n1; }
                    else                                     { v2 = ov2; n2 = on2; }
                    v1 = ov1; n1 = on1;
                } else {
                    if (ov1 > v2 || (ov1 == v2 && on1 < n2)) { v2 = ov1; n2 = on1; }
                }
            }
            float se = 0.f, sv = 0.f;
            #pragma unroll
            for (int nt = 0; nt < 4; ++nt) {
                float e = __expf(lg4[nt] - v1);
                se += e;
                sv += e * d4[nt];
            }
            #pragma unroll
            for (int off = 1; off < 32; off <<= 1) {
                se += __shfl_xor(se, off);
                sv += __shfl_xor(sv, off);
            }
            if (hl == 0) {
                float* s6 = stbuf + (mrow * 8 + w) * 6;
                s6[0] = v1; s6[1] = v2;
                s6[2] = __int_as_float(n1); s6[3] = __int_as_float(n2);
                s6[4] = se; s6[5] = sv;
            }
        }
    }
    __syncthreads();

    // ---- cross-wave merge: wave w handles rows w*8..w*8+7, 8 lanes per row ----
    {
        int row = w * 8 + (lane >> 3), s = lane & 7;
        const float* s6 = stbuf + (row * 8 + s) * 6;
        float v1 = s6[0], v2 = s6[1];
        int n1 = __float_as_int(s6[2]), n2 = __float_as_int(s6[3]);
        float se = s6[4], sv = s6[5];
        #pragma unroll
        for (int off = 1; off < 8; off <<= 1) {
            float ov1 = __shfl_xor(v1, off), ov2 = __shfl_xor(v2, off);
            int   on1 = __shfl_xor(n1, off), on2 = __shfl_xor(n2, off);
            float ose = __shfl_xor(se, off), osv = __shfl_xor(sv, off);
            float myv1 = v1;
            float mv1, mv2; int mn1, mn2;
            if (ov1 > v1 || (ov1 == v1 && on1 < n1)) {
                mv1 = ov1; mn1 = on1;
                if (v1 > ov2 || (v1 == ov2 && n1 < on2)) { mv2 = v1; mn2 = n1; }
                else                                     { mv2 = ov2; mn2 = on2; }
            } else {
                mv1 = v1; mn1 = n1;
                if (ov1 > v2 || (ov1 == v2 && on1 < n2)) { mv2 = ov1; mn2 = on1; }
                else                                     { mv2 = v2; mn2 = n2; }
            }
            float fa = __expf(myv1 - mv1), fb = __expf(ov1 - mv1);
            se = se * fa + ose * fb;
            sv = sv * fa + osv * fb;
            v1 = mv1; n1 = mn1; v2 = mv2; n2 = mn2;
        }
        if (s == 0) {
            int gm = m0 + row;
            out[PRED_OFF + gm] = sv / se;
            bool flagged = (n2 < P_) && ((v1 - v2) < TIE_THR);
            if (!flagged) out[ASSIGN_OFF + gm] = (float)n1;
            rowinfo[row] = flagged ? (n1 | (n2 << 16)) : -1;
        }
    }
    __syncthreads();

    // ---- fp64 tie refinement (wave 0, cooperative) ----
    if (w == 0) {
        for (int row = 0; row < 64; ++row) {
            int info = rowinfo[row];
            if (info < 0) continue;
            int n1 = info & 0xffff, n2 = info >> 16;
            const float* qcol = qb + row;
            double d1 = 0.0, d2 = 0.0, s1 = 0.0, s2 = 0.0;
            for (int cc = lane; cc < C_; cc += 64) {
                double qv = (double)qcol[(size_t)cc * HW_];
                double p1 = (double)pooledT[cc * P_ + n1];
                double p2 = (double)pooledT[cc * P_ + n2];
                d1 += qv * p1; d2 += qv * p2;
                s1 += p1 * p1; s2 += p2 * p2;
            }
            #pragma unroll
            for (int off = 1; off < 64; off <<= 1) {
                d1 += __shfl_xor(d1, off); d2 += __shfl_xor(d2, off);
                s1 += __shfl_xor(s1, off); s2 += __shfl_xor(s2, off);
            }
            double f1 = d1 / fmax(sqrt(s1), (double)EPSN);
            double f2 = d2 / fmax(sqrt(s2), (double)EPSN);
            int best = (f2 > f1 || (f2 == f1 && n2 < n1)) ? n2 : n1;
            if (lane == 0) out[ASSIGN_OFF + m0 + row] = (float)best;
        }
    }
}

extern "C" void kernel_launch(void* const* d_in, const int* in_sizes, int n_in,
                              void* d_out, int out_size, void* d_ws, size_t ws_size,
                              hipStream_t stream) {
    const float* qry   = (const float*)d_in[0];
    const float* sup_x = (const float*)d_in[1];
    const float* sup_y = (const float*)d_in[2];
    float* out = (float*)d_out;
    float* ws  = (float*)d_ws;

    float* pooledT = ws;                       // 512*1024 f32 = 2 MB
    float* rnv     = pooledT + C_ * P_;        // 1024
    float* validf  = rnv + P_;                 // 1024
    short* Bph     = (short*)(validf + P_);    // 32*1024*16 bf16 = 1 MB
    short* Bpl     = Bph + 32 * 1024 * 16;     // 1 MB

    pool_y_kernel<<<4, 256, 0, stream>>>(sup_y, out + GRID_OFF, validf);
    pool_x_kernel<<<B_ * C_ / 4, 256, 0, stream>>>(sup_x, pooledT);
    pack_b_kernel<<<16, 512, 0, stream>>>(pooledT, validf, Bph, Bpl, rnv);
    gemm_fused_kernel<<<B_ * HW_ / 64, 512, 0, stream>>>(qry, Bph, Bpl, pooledT, rnv, out);
}

// Round 6
// 614.276 us; speedup vs baseline: 1.6547x; 1.6547x over previous
//
#include <hip/hip_runtime.h>
#include <math.h>

#define B_      16
#define C_      512
#define HW_     4096
#define P_      1024
#define EPSN    1e-4f
#define TEMP_   20.0f
#define THRESH_ 0.95f
#define NEGINF_ -1e9f
#define TIE_THR 1e-3f

#define PRED_OFF   0
#define ASSIGN_OFF 65536
#define GRID_OFF   131072

typedef short short8 __attribute__((ext_vector_type(8)));
typedef float f32x16 __attribute__((ext_vector_type(16)));

__device__ inline unsigned short f2bf(float f) {
    unsigned u = __float_as_uint(f);
    unsigned r = u + 0x7fffu + ((u >> 16) & 1u);
    return (unsigned short)(r >> 16);
}
__device__ inline float bf2f(unsigned short h) {
    return __uint_as_float((unsigned)h << 16);
}

// ---------------- pool sup_y -> proto_grid + valid ----------------
__global__ void pool_y_kernel(const float* __restrict__ sup_y,
                              float* __restrict__ out_grid,
                              float* __restrict__ validf) {
    int p = blockIdx.x * blockDim.x + threadIdx.x;
    if (p >= P_) return;
    int b = p >> 6, cell = p & 63, gy = cell >> 3, gx = cell & 7;
    const float* base = sup_y + b * HW_ + gy * 8 * 64 + gx * 8;
    float s = 0.f;
    #pragma unroll
    for (int r = 0; r < 8; ++r)
        #pragma unroll
        for (int c = 0; c < 8; ++c) s += base[r * 64 + c];
    float avg = s * (1.0f / 64.0f);
    out_grid[p] = (avg < THRESH_) ? 0.0f : avg;
    validf[p]   = (avg > THRESH_) ? 1.0f : 0.0f;
}

// ---------------- pool sup_x -> pooledT[c][p], float4 loads ----------------
__global__ __launch_bounds__(256) void pool_x_kernel(const float* __restrict__ sup_x,
                                                     float* __restrict__ pooledT) {
    int blk = blockIdx.x * 4 + (threadIdx.x >> 6);   // b*C_ + c
    int b = blk >> 9, c = blk & 511;
    int lane = threadIdx.x & 63;
    int cq = lane & 15, rq = lane >> 4;
    const float* base = sup_x + (size_t)(b * C_ + c) * HW_;
    float acc[8];
    #pragma unroll
    for (int g = 0; g < 8; ++g) acc[g] = 0.f;
    #pragma unroll
    for (int i = 0; i < 16; ++i) {
        int row = 4 * i + rq;
        float4 v = *(const float4*)(base + row * 64 + cq * 4);
        acc[i >> 1] += (v.x + v.y) + (v.z + v.w);
    }
    #pragma unroll
    for (int g = 0; g < 8; ++g) {
        acc[g] += __shfl_xor(acc[g], 1);    // cq pair within gx
        acc[g] += __shfl_xor(acc[g], 16);   // rq
        acc[g] += __shfl_xor(acc[g], 32);   // rq
    }
    if (rq == 0 && (cq & 1) == 0) {
        int gx = cq >> 1;
        #pragma unroll
        for (int gy = 0; gy < 8; ++gy)
            pooledT[c * P_ + b * 64 + gy * 8 + gx] = acc[gy] * (1.0f / 64.0f);
    }
}

// ---------------- merged: pack protos to MFMA B order + per-proto 1/norm ----
__global__ __launch_bounds__(512) void pack_b_kernel(const float* __restrict__ pooledT,
                                                     const float* __restrict__ validf,
                                                     short* __restrict__ Bph,
                                                     short* __restrict__ Bpl,
                                                     float* __restrict__ rnv) {
    __shared__ double ssred[8][64];
    int nl = threadIdx.x & 63;
    int w  = threadIdx.x >> 6;            // 0..7 -> channel chunk
    int n  = blockIdx.x * 64 + nl;
    double ss = 0.0;
    for (int c8i = 0; c8i < 8; ++c8i) {
        int c8 = w * 8 + c8i;
        unsigned short vh[8], vl[8];
        #pragma unroll
        for (int j = 0; j < 8; ++j) {
            float p = pooledT[(c8 * 8 + j) * P_ + n];
            ss += (double)p * (double)p;
            unsigned short h = f2bf(p);
            vh[j] = h;
            vl[j] = f2bf(p - bf2f(h));
        }
        uint4 uh, ul;
        uh.x = (unsigned)vh[0] | ((unsigned)vh[1] << 16);
        uh.y = (unsigned)vh[2] | ((unsigned)vh[3] << 16);
        uh.z = (unsigned)vh[4] | ((unsigned)vh[5] << 16);
        uh.w = (unsigned)vh[6] | ((unsigned)vh[7] << 16);
        ul.x = (unsigned)vl[0] | ((unsigned)vl[1] << 16);
        ul.y = (unsigned)vl[2] | ((unsigned)vl[3] << 16);
        ul.z = (unsigned)vl[4] | ((unsigned)vl[5] << 16);
        ul.w = (unsigned)vl[6] | ((unsigned)vl[7] << 16);
        int sk = c8 >> 1, kh = c8 & 1;
        *(uint4*)&Bph[sk * 16384 + n * 16 + kh * 8] = uh;
        *(uint4*)&Bpl[sk * 16384 + n * 16 + kh * 8] = ul;
    }
    ssred[w][nl] = ss;
    __syncthreads();
    if (threadIdx.x < 64) {
        double s = 0.0;
        #pragma unroll
        for (int q = 0; q < 8; ++q) s += ssred[q][threadIdx.x];
        int nn = blockIdx.x * 64 + threadIdx.x;
        float rn = 1.0f / fmaxf((float)sqrt(s), EPSN);
        rnv[nn] = (validf[nn] > 0.5f) ? rn : 0.0f;
    }
}

// ---------------- fused MFMA GEMM + softmax + argmax ----------------
// grid 1024 blocks (64 px x 1024 protos), 1024 threads (16 waves).
// OCCUPANCY FIX: per-wave output halved to 1 m-tile x 4 n-tiles -> acc = 64
// AGPR; B single-buffered (32 VGPR) + A 1-deep LDS prefetch -> ~124 total
// regs/wave, enforced by __launch_bounds__(1024,4) => 4 waves/SIMD,
// 16 waves/CU (2x rounds 0-5, which were pinned at 2 waves/SIMD by 252 regs).
// Same proven R2 structure: full A panel (128 KB hi+lo bf16) staged ONCE in
// fragment order (conflict-free ds_read_b128), barrier-free K loop.
// GEMM accumulation order unchanged -> dists bit-identical to round 2.
__global__ __launch_bounds__(1024, 4) void gemm_fused_kernel(
        const float* __restrict__ qry,
        const short* __restrict__ Bph,
        const short* __restrict__ Bpl,
        const float* __restrict__ pooledT,
        const float* __restrict__ rnv,
        float* __restrict__ out) {
    __shared__ short Ah2[32 * 1024];      // 64 KB  [c8][px][8] hi bf16
    __shared__ short Al2[32 * 1024];      // 64 KB  lo bf16
    __shared__ float rqs_lds[64];
    __shared__ int rowinfo[64];
    // post-K-loop aliases into dead Ah2:
    float* ss_part = (float*)Ah2;                 // [1024*4]   bytes 0..16383
    float* stbuf   = (float*)Ah2 + 4096;          // [64][8][6] bytes 16384..28671

    int m0 = blockIdx.x * 64;
    int b = m0 >> 12;
    int hw0 = m0 & 4095;
    int tid = threadIdx.x;
    int w = tid >> 6;                  // 0..15
    int lane = tid & 63;
    int hl = lane & 31, half = lane >> 5;
    int wm = w >> 3, wn = w & 7;       // wave -> (m-tile, n-range)
    int nb = wn * 128;

    const float* qb = qry + (size_t)b * (C_ * HW_) + hw0;
    const short* bh_base = Bph + ((nb + hl) * 16 + half * 8);
    const short* bl_base = Bpl + ((nb + hl) * 16 + half * 8);

    // ---- stage full A panel: thread = (c8 = tid>>4 in 0..63, pg = tid&15) ----
    float ss4[4] = {0.f, 0.f, 0.f, 0.f};
    {
        int pg = tid & 15;
        int c8 = tid >> 4;
        const float* src = qb + (size_t)(c8 * 8) * HW_ + pg * 4;
        float4 q[8];
        #pragma unroll
        for (int j = 0; j < 8; ++j)
            q[j] = *(const float4*)(src + (size_t)j * HW_);
        #pragma unroll
        for (int pp = 0; pp < 4; ++pp) {
            unsigned uh[4], ul[4];
            #pragma unroll
            for (int jj = 0; jj < 4; ++jj) {
                float a0 = ((const float*)&q[2 * jj])[pp];
                float a1 = ((const float*)&q[2 * jj + 1])[pp];
                unsigned short h0 = f2bf(a0), h1 = f2bf(a1);
                float r0 = a0 - bf2f(h0), r1 = a1 - bf2f(h1);
                unsigned short l0 = f2bf(r0), l1 = f2bf(r1);
                uh[jj] = (unsigned)h0 | ((unsigned)h1 << 16);
                ul[jj] = (unsigned)l0 | ((unsigned)l1 << 16);
                ss4[pp] += a0 * a0 + a1 * a1;
            }
            uint4 UH, UL;
            UH.x = uh[0]; UH.y = uh[1]; UH.z = uh[2]; UH.w = uh[3];
            UL.x = ul[0]; UL.y = ul[1]; UL.z = ul[2]; UL.w = ul[3];
            int off = (c8 * 64 + pg * 4 + pp) * 8;   // shorts, 16B aligned
            *(uint4*)&Ah2[off] = UH;
            *(uint4*)&Al2[off] = UL;
        }
    }
    __syncthreads();

    f32x16 zero16 = {0.f,0.f,0.f,0.f,0.f,0.f,0.f,0.f,0.f,0.f,0.f,0.f,0.f,0.f,0.f,0.f};
    f32x16 acc[4];
    #pragma unroll
    for (int nt = 0; nt < 4; ++nt) acc[nt] = zero16;

    // ---- prologue: B(0) + A(0) ----
    short8 bhc[4], blc[4], ahc, alc, ahn, aln;
    #pragma unroll
    for (int nt = 0; nt < 4; ++nt) {
        bhc[nt] = *(const short8*)(bh_base + nt * 512);
        blc[nt] = *(const short8*)(bl_base + nt * 512);
    }
    {
        int a0off = ((half) * 64 + wm * 32 + hl) * 8;
        ahc = *(const short8*)&Ah2[a0off];
        alc = *(const short8*)&Al2[a0off];
    }

    // ---- barrier-free K loop: B single-buffered, A 1-deep LDS prefetch ----
    for (int sk = 0; sk < 32; ++sk) {
        int nsk = sk + 1;
        if (nsk < 32) {
            int aoff = (((nsk * 2) + half) * 64 + wm * 32 + hl) * 8;
            ahn = *(const short8*)&Ah2[aoff];
            aln = *(const short8*)&Al2[aoff];
        }
        #pragma unroll
        for (int nt = 0; nt < 4; ++nt) {
            acc[nt] = __builtin_amdgcn_mfma_f32_32x32x16_bf16(ahc, bhc[nt], acc[nt], 0, 0, 0);
            acc[nt] = __builtin_amdgcn_mfma_f32_32x32x16_bf16(alc, bhc[nt], acc[nt], 0, 0, 0);
            acc[nt] = __builtin_amdgcn_mfma_f32_32x32x16_bf16(ahc, blc[nt], acc[nt], 0, 0, 0);
        }
        if (nsk < 32) {
            const short* bh_p = bh_base + nsk * 16384;
            const short* bl_p = bl_base + nsk * 16384;
            #pragma unroll
            for (int nt = 0; nt < 4; ++nt) {
                bhc[nt] = *(const short8*)(bh_p + nt * 512);
                blc[nt] = *(const short8*)(bl_p + nt * 512);
            }
            ahc = ahn; alc = aln;
        }
    }
    __syncthreads();   // Ah2/Al2 dead; aliased scratch phase begins

    // ---- per-pixel 1/||q|| ----
    *(float4*)&ss_part[tid * 4] = *(const float4*)ss4;
    __syncthreads();
    if (tid < 64) {
        int pg2 = tid >> 2, pp = tid & 3;
        float s = 0.f;
        #pragma unroll
        for (int k = 0; k < 64; ++k) s += ss_part[(k * 16 + pg2) * 4 + pp];
        rqs_lds[tid] = 1.0f / fmaxf(sqrtf(s), EPSN);
    }
    __syncthreads();

    // ---- per-wave epilogue: scale, top2, softmax sums over this wave's 128 n ----
    float rn4[4];
    #pragma unroll
    for (int nt = 0; nt < 4; ++nt) rn4[nt] = rnv[nb + nt * 32 + hl];

    #pragma unroll
    for (int r = 0; r < 16; ++r) {
        int mrow = wm * 32 + (r & 3) + 8 * (r >> 2) + 4 * half;
        float scale = rqs_lds[mrow] * TEMP_;
        float d4[4], lg4[4];
        float v1 = -3e38f, v2 = -3e38f;
        int n1 = P_, n2 = P_;
        #pragma unroll
        for (int nt = 0; nt < 4; ++nt) {
            float dd = acc[nt][r] * rn4[nt] * scale;
            float lg = (rn4[nt] > 0.f) ? dd : NEGINF_;
            d4[nt] = dd; lg4[nt] = lg;
            int n = nb + nt * 32 + hl;
            if (lg > v1 || (lg == v1 && n < n1)) {
                v2 = v1; n2 = n1; v1 = lg; n1 = n;
            } else if (lg > v2 || (lg == v2 && n < n2)) {
                v2 = lg; n2 = n;
            }
        }
        #pragma unroll
        for (int off = 1; off < 32; off <<= 1) {
            float ov1 = __shfl_xor(v1, off), ov2 = __shfl_xor(v2, off);
            int   on1 = __shfl_xor(n1, off), on2 = __shfl_xor(n2, off);
            if (ov1 > v1 || (ov1 == v1 && on1 < n1)) {
                if (v1 > ov2 || (v1 == ov2 && n1 < on2)) { v2 = v1; n2 = n1; }
                else                                     { v2 = ov2; n2 = on2; }
                v1 = ov1; n1 = on1;
            } else {
                if (ov1 > v2 || (ov1 == v2 && on1 < n2)) { v2 = ov1; n2 = on1; }
            }
        }
        float se = 0.f, sv = 0.f;
        #pragma unroll
        for (int nt = 0; nt < 4; ++nt) {
            float e = __expf(lg4[nt] - v1);
            se += e;
            sv += e * d4[nt];
        }
        #pragma unroll
        for (int off = 1; off < 32; off <<= 1) {
            se += __shfl_xor(se, off);
            sv += __shfl_xor(sv, off);
        }
        if (hl == 0) {
            float* s6 = stbuf + (mrow * 8 + wn) * 6;
            s6[0] = v1; s6[1] = v2;
            s6[2] = __int_as_float(n1); s6[3] = __int_as_float(n2);
            s6[4] = se; s6[5] = sv;
        }
    }
    __syncthreads();

    // ---- cross-wave merge: waves 0..7, wave w handles rows w*8..w*8+7 ----
    if (w < 8) {
        int row = w * 8 + (lane >> 3), s = lane & 7;
        const float* s6 = stbuf + (row * 8 + s) * 6;
        float v1 = s6[0], v2 = s6[1];
        int n1 = __float_as_int(s6[2]), n2 = __float_as_int(s6[3]);
        float se = s6[4], sv = s6[5];
        #pragma unroll
        for (int off = 1; off < 8; off <<= 1) {
            float ov1 = __shfl_xor(v1, off), ov2 = __shfl_xor(v2, off);
            int   on1 = __shfl_xor(n1, off), on2 = __shfl_xor(n2, off);
            float ose = __shfl_xor(se, off), osv = __shfl_xor(sv, off);
            float myv1 = v1;
            float mv1, mv2; int mn1, mn2;
            if (ov1 > v1 || (ov1 == v1 && on1 < n1)) {
                mv1 = ov1; mn1 = on1;
                if (v1 > ov2 || (v1 == ov2 && n1 < on2)) { mv2 = v1; mn2 = n1; }
                else                                     { mv2 = ov2; mn2 = on2; }
            } else {
                mv1 = v1; mn1 = n1;
                if (ov1 > v2 || (ov1 == v2 && on1 < n2)) { mv2 = ov1; mn2 = on1; }
                else                                     { mv2 = v2; mn2 = n2; }
            }
            float fa = __expf(myv1 - mv1), fb = __expf(ov1 - mv1);
            se = se * fa + ose * fb;
            sv = sv * fa + osv * fb;
            v1 = mv1; n1 = mn1; v2 = mv2; n2 = mn2;
        }
        if (s == 0) {
            int gm = m0 + row;
            out[PRED_OFF + gm] = sv / se;
            bool flagged = (n2 < P_) && ((v1 - v2) < TIE_THR);
            if (!flagged) out[ASSIGN_OFF + gm] = (float)n1;
            rowinfo[row] = flagged ? (n1 | (n2 << 16)) : -1;
        }
    }
    __syncthreads();

    // ---- fp64 tie refinement (wave 0, cooperative) ----
    if (w == 0) {
        for (int row = 0; row < 64; ++row) {
            int info = rowinfo[row];
            if (info < 0) continue;
            int n1 = info & 0xffff, n2 = info >> 16;
            const float* qcol = qb + row;
            double d1 = 0.0, d2 = 0.0, s1 = 0.0, s2 = 0.0;
            for (int cc = lane; cc < C_; cc += 64) {
                double qv = (double)qcol[(size_t)cc * HW_];
                double p1 = (double)pooledT[cc * P_ + n1];
                double p2 = (double)pooledT[cc * P_ + n2];
                d1 += qv * p1; d2 += qv * p2;
                s1 += p1 * p1; s2 += p2 * p2;
            }
            #pragma unroll
            for (int off = 1; off < 64; off <<= 1) {
                d1 += __shfl_xor(d1, off); d2 += __shfl_xor(d2, off);
                s1 += __shfl_xor(s1, off); s2 += __shfl_xor(s2, off);
            }
            double f1 = d1 / fmax(sqrt(s1), (double)EPSN);
            double f2 = d2 / fmax(sqrt(s2), (double)EPSN);
            int best = (f2 > f1 || (f2 == f1 && n2 < n1)) ? n2 : n1;
            if (lane == 0) out[ASSIGN_OFF + m0 + row] = (float)best;
        }
    }
}

extern "C" void kernel_launch(void* const* d_in, const int* in_sizes, int n_in,
                              void* d_out, int out_size, void* d_ws, size_t ws_size,
                              hipStream_t stream) {
    const float* qry   = (const float*)d_in[0];
    const float* sup_x = (const float*)d_in[1];
    const float* sup_y = (const float*)d_in[2];
    float* out = (float*)d_out;
    float* ws  = (float*)d_ws;

    float* pooledT = ws;                       // 512*1024 f32 = 2 MB
    float* rnv     = pooledT + C_ * P_;        // 1024
    float* validf  = rnv + P_;                 // 1024
    short* Bph     = (short*)(validf + P_);    // 32*1024*16 bf16 = 1 MB
    short* Bpl     = Bph + 32 * 1024 * 16;     // 1 MB

    pool_y_kernel<<<4, 256, 0, stream>>>(sup_y, out + GRID_OFF, validf);
    pool_x_kernel<<<B_ * C_ / 4, 256, 0, stream>>>(sup_x, pooledT);
    pack_b_kernel<<<16, 512, 0, stream>>>(pooledT, validf, Bph, Bpl, rnv);
    gemm_fused_kernel<<<B_ * HW_ / 64, 1024, 0, stream>>>(qry, Bph, Bpl, pooledT, rnv, out);
}